// Round 5
// baseline (168.730 us; speedup 1.0000x reference)
//
#include <hip/hip_runtime.h>
#include <hip/hip_bf16.h>
#include <stdint.h>

// Shape fixed by reference: B=2, S=1024 -> M=2048; N=4096; K=4096
#define M_DIM 2048
#define N_DIM 4096
#define K_DIM 4096

#define BM 256
#define BN 128
#define BK 128            // int8 elems per K-tile = 128 B per row

#define ATILE (BM * BK)   // 32 KiB per A buffer
#define BTILE (BN * BK)   // 16 KiB per B buffer

typedef __attribute__((ext_vector_type(4))) int int4v;

__device__ __forceinline__ void load_lds16(const void* g, void* l) {
    __builtin_amdgcn_global_load_lds(
        (const __attribute__((address_space(1))) void*)g,
        (__attribute__((address_space(3))) void*)l,
        16, 0, 0);
}

// ---------- x: fp32 [M,K] -> int8 per-row dynamic quant; sx[row] = rowmax/127 ----------
__global__ __launch_bounds__(256) void quant_x(const float* __restrict__ x,
                                               int8_t* __restrict__ Aq,
                                               float* __restrict__ sx) {
    const int row = blockIdx.x;
    const int tid = threadIdx.x;
    const float4* xr = (const float4*)(x + (size_t)row * K_DIM);

    float4 v[4];
    float mx = 0.f;
#pragma unroll
    for (int p = 0; p < 4; p++) {
        v[p] = xr[p * 256 + tid];
        mx = fmaxf(mx, fmaxf(fmaxf(fabsf(v[p].x), fabsf(v[p].y)),
                             fmaxf(fabsf(v[p].z), fabsf(v[p].w))));
    }
#pragma unroll
    for (int off = 32; off >= 1; off >>= 1)
        mx = fmaxf(mx, __shfl_xor(mx, off, 64));

    __shared__ float wmax[4];
    __shared__ float smax;
    if ((tid & 63) == 0) wmax[tid >> 6] = mx;
    __syncthreads();
    if (tid == 0) {
        float m = fmaxf(fmaxf(wmax[0], wmax[1]), fmaxf(wmax[2], wmax[3]));
        m = fmaxf(m, 1e-20f);
        smax = m;
        sx[row] = m * (1.0f / 127.0f);
    }
    __syncthreads();
    const float inv = 127.0f / smax;

    int* out = (int*)Aq + (size_t)row * (K_DIM / 4);
#pragma unroll
    for (int p = 0; p < 4; p++) {
        int q0 = (int)__builtin_rintf(v[p].x * inv);
        int q1 = (int)__builtin_rintf(v[p].y * inv);
        int q2 = (int)__builtin_rintf(v[p].z * inv);
        int q3 = (int)__builtin_rintf(v[p].w * inv);
        q0 = max(-127, min(127, q0)); q1 = max(-127, min(127, q1));
        q2 = max(-127, min(127, q2)); q3 = max(-127, min(127, q3));
        out[p * 256 + tid] = (q0 & 255) | ((q1 & 255) << 8) |
                             ((q2 & 255) << 16) | ((q3 & 255) << 24);
    }
}

// ---------- w: int32 [N,K] (values in [-128,127]) -> int8 (low-byte, exact) ----------
__global__ __launch_bounds__(256) void cvt_w8(const int* __restrict__ w,
                                              int8_t* __restrict__ Bq) {
    size_t i = ((size_t)blockIdx.x * 256 + threadIdx.x) * 16;
    int4 a0 = *(const int4*)(w + i);
    int4 a1 = *(const int4*)(w + i + 4);
    int4 a2 = *(const int4*)(w + i + 8);
    int4 a3 = *(const int4*)(w + i + 12);
    uint4 t;
    t.x = (a0.x & 255) | ((a0.y & 255) << 8) | ((a0.z & 255) << 16) | ((a0.w & 255) << 24);
    t.y = (a1.x & 255) | ((a1.y & 255) << 8) | ((a1.z & 255) << 16) | ((a1.w & 255) << 24);
    t.z = (a2.x & 255) | ((a2.y & 255) << 8) | ((a2.z & 255) << 16) | ((a2.w & 255) << 24);
    t.w = (a3.x & 255) | ((a3.y & 255) << 8) | ((a3.z & 255) << 16) | ((a3.w & 255) << 24);
    *(uint4*)(Bq + i) = t;
}

// ---------- GEMM: C = Aq[M,K] x Bq[N,K]^T (i8 MFMA, i32 acc), dequant epilogue ----------
// Round-5 structure: 256x128 tile, BK=128, 1024 threads = 16 waves in 4x4 (wave
// owns 64x32, acc[4][2] of 16x16x64 i8). Rationale: per-iter cycle cost measured
// ~constant (~2800-3100 cyc) across r3/r4 regardless of content -> amortize the
// fixed floor over 2x MACs/iter; compute:staging ratio 1.0 -> 1.33.
// Dbuf LDS (96 KiB, 1 block/CU, grid 256 = 1/CU exactly): glds prefetch for tile
// k+1 issued before compute of tile k; one barrier per iter.
// XOR swizzle (cg_phys = cg_log ^ (row&7)) on the GLOBAL source address keeps
// ds_read bank conflicts at 0 (verified r2-r4); glds LDS dest fixed at base+lane*16.
// A/B fragments share the same per-lane byte pattern -> any lane->k permutation
// inside the i8 MFMA cancels; only the shape-determined C/D layout matters.

__global__ __launch_bounds__(1024, 4) void gemm_bt_i8(
    const int8_t* __restrict__ A,      // [M,K] int8
    const int8_t* __restrict__ B,      // [N,K] int8
    const float*  __restrict__ sx,     // [M] row dequant scale
    const float*  __restrict__ scales, // [N]
    const float*  __restrict__ bias,   // [N]
    float* __restrict__ C)             // [M,N]
{
    __shared__ __align__(16) int8_t As[2 * ATILE];  // 64 KiB
    __shared__ __align__(16) int8_t Bs[2 * BTILE];  // 32 KiB

    const int tid  = threadIdx.x;
    const int bm   = blockIdx.y;
    const int bn   = blockIdx.x;
    const int lane = tid & 63;
    const int wave = tid >> 6;           // 0..15
    const int wm   = (wave >> 2) * 64;   // 0,64,128,192
    const int wn   = (wave & 3) * 32;    // 0,32,64,96
    const int l16  = lane & 15;
    const int quad = lane >> 4;
    const int swz  = l16 & 7;

    // Staging: 1024 thr x 16 B = 16 KiB/instr; A tile = 2 instrs, B tile = 1.
    // thread t -> LDS (row = t>>3 (+128 for A instr 2), phys colgroup = t&7);
    // global colgroup = phys ^ (row&7). LDS byte addr = 16*t: linear in tid.
    const int srow = tid >> 3;           // 0..127
    const int cgp  = tid & 7;
    const int cgl  = cgp ^ (srow & 7);   // (srow+128)&7 == srow&7

    const int8_t* ga0 = A + (size_t)(bm * BM + srow)       * K_DIM + cgl * 16;
    const int8_t* ga1 = A + (size_t)(bm * BM + 128 + srow) * K_DIM + cgl * 16;
    const int8_t* gb0 = B + (size_t)(bn * BN + srow)       * K_DIM + cgl * 16;
    const int la0 = srow * BK + cgp * 16;          // == tid*16
    const int la1 = ATILE / 2 + la0;               // second half of A buffer

    // Prologue: stage tile 0 into buffer 0.
    load_lds16(ga0, As + la0);
    load_lds16(ga1, As + la1);
    load_lds16(gb0, Bs + la0);

    int4v acc[4][2] = {};

    int cur = 0;
    for (int k0 = 0; k0 < K_DIM; k0 += BK, cur ^= 1) {
        __syncthreads();   // drains glds for buf[cur]; all waves done with buf[cur^1]

        const int kn = k0 + BK;
        if (kn < K_DIM) {  // prefetch next tile, in flight during compute
            const int nb = (cur ^ 1);
            load_lds16(ga0 + kn, As + nb * ATILE + la0);
            load_lds16(ga1 + kn, As + nb * ATILE + la1);
            load_lds16(gb0 + kn, Bs + nb * BTILE + la0);
        }

        const int8_t* Ab = As + cur * ATILE;
        const int8_t* Bb = Bs + cur * BTILE;

#pragma unroll
        for (int h = 0; h < 2; h++) {
            const int cp = (h * 4 + quad) ^ swz;   // physical colgroup to read
            int4v af[4], bfr[2];
#pragma unroll
            for (int i = 0; i < 4; i++)
                af[i] = *(const int4v*)(Ab + (wm + i * 16 + l16) * BK + cp * 16);
#pragma unroll
            for (int j = 0; j < 2; j++)
                bfr[j] = *(const int4v*)(Bb + (wn + j * 16 + l16) * BK + cp * 16);
#pragma unroll
            for (int i = 0; i < 4; i++)
#pragma unroll
                for (int j = 0; j < 2; j++)
                    acc[i][j] = __builtin_amdgcn_mfma_i32_16x16x64_i8(
                        af[i], bfr[j], acc[i][j], 0, 0, 0);
        }
    }

    // Row dequant scales for this lane's 16 output rows.
    float sxr[16];
#pragma unroll
    for (int i = 0; i < 4; i++)
#pragma unroll
        for (int r = 0; r < 4; r++)
            sxr[i * 4 + r] = sx[bm * BM + wm + i * 16 + quad * 4 + r];

    // Epilogue. C/D layout (shape-determined, verified): col = lane&15, row = quad*4 + reg.
#pragma unroll
    for (int j = 0; j < 2; j++) {
        const int col = bn * BN + wn + j * 16 + l16;
        const float s = scales[col];
        const float b = bias[col];
#pragma unroll
        for (int i = 0; i < 4; i++) {
            const int row0 = bm * BM + wm + i * 16 + quad * 4;
#pragma unroll
            for (int r = 0; r < 4; r++) {
                C[(size_t)(row0 + r) * N_DIM + col] =
                    (float)acc[i][j][r] * (sxr[i * 4 + r] * s) + b;
            }
        }
    }
}

// ---------- launch ----------

extern "C" void kernel_launch(void* const* d_in, const int* in_sizes, int n_in,
                              void* d_out, int out_size, void* d_ws, size_t ws_size,
                              hipStream_t stream) {
    const float* x      = (const float*)d_in[0];   // [2,1024,4096] fp32
    const int*   w      = (const int*)d_in[1];     // [4096,4096] int, values in [-128,127]
    const float* scales = (const float*)d_in[2];   // [4096]
    const float* bias   = (const float*)d_in[3];   // [4096]
    float*       out    = (float*)d_out;           // [2,1024,4096] fp32

    int8_t* Aq = (int8_t*)d_ws;                                        // 8 MiB
    int8_t* Bq = (int8_t*)d_ws + (size_t)M_DIM * K_DIM;                // 16 MiB
    float*  sx = (float*)((int8_t*)d_ws + (size_t)(M_DIM + N_DIM) * K_DIM); // 8 KiB

    quant_x<<<M_DIM, 256, 0, stream>>>(x, Aq, sx);
    cvt_w8<<<(int)((size_t)N_DIM * K_DIM / 16 / 256), 256, 0, stream>>>(w, Bq);

    dim3 grid(N_DIM / BN, M_DIM / BM);  // (32, 8) = 256 blocks = 1/CU
    gemm_bt_i8<<<grid, 1024, 0, stream>>>(Aq, Bq, sx, scales, bias, out);
}